// Round 10
// baseline (17679.242 us; speedup 1.0000x reference)
//
#include <hip/hip_runtime.h>
#include <math.h>

#define T_STEPS 4096
#define HID     1024
#define G4      4096   // 4*HID gate rows
#define NB      64     // recurrence blocks
#define TPB     512    // 8 waves per block

// ---- agent-scope atomic helpers ----
__device__ __forceinline__ unsigned ld_ctr_acq(const unsigned* p) {
    return __hip_atomic_load(p, __ATOMIC_ACQUIRE, __HIP_MEMORY_SCOPE_AGENT);
}
__device__ __forceinline__ void add_ctr_rel(unsigned* p) {
    __hip_atomic_fetch_add(p, 1u, __ATOMIC_RELEASE, __HIP_MEMORY_SCOPE_AGENT);
}
__device__ __forceinline__ unsigned long long ld_pair(const float* p) {
    return __hip_atomic_load((const unsigned long long*)p,
                             __ATOMIC_RELAXED, __HIP_MEMORY_SCOPE_AGENT);
}
__device__ __forceinline__ void st_h(float* p, float v) {
    __hip_atomic_store(p, v, __ATOMIC_RELAXED, __HIP_MEMORY_SCOPE_AGENT);
}
__device__ __forceinline__ float fsigmoid(float x) {
    return __fdividef(1.0f, 1.0f + __expf(-x));
}
__device__ __forceinline__ float ftanh(float x) {
    return __fdividef(2.0f, 1.0f + __expf(-2.0f * x)) - 1.0f;
}

// ---------------------------------------------------------------------------
// Kernel 1: xg[t][r] = dot(x[t,:], w_ih[r,:]) + b_ih[r] + b_hh[r]
// f32 GEMM, 64x64 tile, K-chunk 32, 256 threads, 4x4 per thread.
// Block (0,0) thread 0 also zeroes the step counter (graph-replay reset).
// ---------------------------------------------------------------------------
__global__ __launch_bounds__(256) void xg_gemm(
    const float* __restrict__ x, const float* __restrict__ w_ih,
    const float* __restrict__ b_ih, const float* __restrict__ b_hh,
    float* __restrict__ xg, unsigned* __restrict__ ctr)
{
    if (blockIdx.x == 0 && blockIdx.y == 0 && threadIdx.x == 0)
        __hip_atomic_store(ctr, 0u, __ATOMIC_RELAXED, __HIP_MEMORY_SCOPE_AGENT);

    __shared__ float Xs[32][68];   // [k][m], pad kills conflicts
    __shared__ float Ws[32][68];   // [k][n]

    const int t0  = blockIdx.y * 64;
    const int n0  = blockIdx.x * 64;
    const int thr = threadIdx.x;
    const int tx  = thr & 15;      // n-group
    const int ty  = thr >> 4;      // m-group

    float acc[4][4] = {};

    for (int kk = 0; kk < 1024; kk += 32) {
        #pragma unroll
        for (int i = 0; i < 2; i++) {
            int flat = thr + i * 256;       // 0..511
            int m    = flat >> 3;           // 0..63
            int kc   = flat & 7;            // k-chunk (4 floats)
            float4 xv = *(const float4*)(x    + (size_t)(t0 + m) * 1024 + kk + kc * 4);
            float4 wv = *(const float4*)(w_ih + (size_t)(n0 + m) * 1024 + kk + kc * 4);
            Xs[kc*4+0][m] = xv.x; Xs[kc*4+1][m] = xv.y;
            Xs[kc*4+2][m] = xv.z; Xs[kc*4+3][m] = xv.w;
            Ws[kc*4+0][m] = wv.x; Ws[kc*4+1][m] = wv.y;
            Ws[kc*4+2][m] = wv.z; Ws[kc*4+3][m] = wv.w;
        }
        __syncthreads();
        #pragma unroll
        for (int k = 0; k < 32; k++) {
            float4 a4 = *(const float4*)&Xs[k][ty * 4];
            float4 b4 = *(const float4*)&Ws[k][tx * 4];
            float av[4] = {a4.x, a4.y, a4.z, a4.w};
            float bv[4] = {b4.x, b4.y, b4.z, b4.w};
            #pragma unroll
            for (int i = 0; i < 4; i++)
                #pragma unroll
                for (int j = 0; j < 4; j++)
                    acc[i][j] = fmaf(av[i], bv[j], acc[i][j]);
        }
        __syncthreads();
    }

    float4 bi = *(const float4*)(b_ih + n0 + tx * 4);
    float4 bh = *(const float4*)(b_hh + n0 + tx * 4);
    float bb[4] = {bi.x + bh.x, bi.y + bh.y, bi.z + bh.z, bi.w + bh.w};
    #pragma unroll
    for (int i = 0; i < 4; i++) {
        float4 o;
        o.x = acc[i][0] + bb[0]; o.y = acc[i][1] + bb[1];
        o.z = acc[i][2] + bb[2]; o.w = acc[i][3] + bb[3];
        *(float4*)(xg + (size_t)(t0 + ty * 4 + i) * G4 + n0 + tx * 4) = o;
    }
}

// ---------------------------------------------------------------------------
// Kernel 2: persistent recurrence. 64 blocks x 512 threads (r2's proven
// datapath), counter-based sync replacing per-word tag spinning:
//   producers: relaxed f32 stores -> __syncthreads (drains vmcnt, stores at
//   device-visible point) -> thread 0 fetch_add(ctr,1,RELEASE).
//   consumers: ONLY thread 0 spins (acquire) until ctr >= 64*(t+1); others
//   park at s_barrier; then ONE one-shot relaxed u64 load per thread.
// 64 spinning lanes chip-wide instead of 32K -> no fabric congestion.
// Block b owns units [16b,16b+16). Wave rg owns units (16b+2rg, +1) x 4
// gates = 8 rows; lane ec owns cols [16ec,16ec+16).
// ---------------------------------------------------------------------------
__global__ __launch_bounds__(512, 2) void lstm_rec(
    const float* __restrict__ xg, const float* __restrict__ w_hh,
    const float* __restrict__ h0, const float* __restrict__ c0,
    const float* __restrict__ w_out, const float* __restrict__ b_out,
    float* __restrict__ h_pub,        // [2][HID] f32 (untagged)
    unsigned* __restrict__ ctr,       // step counter
    float* __restrict__ out)
{
    __shared__ float h_lds[2][64 * 20];   // double-buffered, stride-20 chunks
    __shared__ float red_lds[8];

    const int thr = threadIdx.x;
    const int b   = blockIdx.x;
    const int rg  = thr >> 6;          // wave 0..7
    const int ec  = thr & 63;          // lane 0..63

    // this wave's 8 rows: gate = rr&3, unit-delta = rr>>2
    int grow[8];
    #pragma unroll
    for (int rr = 0; rr < 8; rr++)
        grow[rr] = (rr & 3) * HID + b * 16 + 2 * rg + (rr >> 2);

    // ---- weights: 128 floats/thread, streamed from L2 each step (proven
    // not the bottleneck in r8; L2-resident at 2MB/XCD)
    float4 w[8][4];
    #pragma unroll
    for (int rr = 0; rr < 8; rr++) {
        const float* wr = w_hh + (size_t)grow[rr] * HID + ec * 16;
        #pragma unroll
        for (int q = 0; q < 4; q++)
            w[rr][q] = *(const float4*)(wr + q * 4);
    }

    // ---- init: c on lanes 0/4 of each wave; publish h0; signal
    const int myunit = b * 16 + 2 * rg + (ec >> 2);   // valid on lanes 0,4
    float c = 0.0f;
    if (ec == 0 || ec == 4) {
        c = c0[myunit];
        st_h(&h_pub[0 * HID + myunit], h0[myunit]);
    }
    __syncthreads();                    // drain init stores (vmcnt 0)
    if (thr == 0) add_ctr_rel(ctr);     // counter: 64 when all blocks ready

    const int u0 = 2 * thr;            // this thread's two staged h units
    const int l0 = (u0 >> 4) * 20 + (u0 & 15);
    const int xrow = grow[ec & 7];     // xg row whose total this lane holds

    for (int t = 0; t < T_STEPS; t++) {
        const int p = t & 1;

        // xg prefetch (independent of the handoff)
        float xgv = xg[(size_t)t * G4 + xrow];

        // ---- single-spinner sync: thread 0 waits for all 64 signals
        if (thr == 0) {
            const unsigned target = 64u * (unsigned)(t + 1);
            while (ld_ctr_acq(ctr) < target) { }
        }
        __syncthreads();

        // ---- one-shot h fetch: one u64 (two f32) per thread
        unsigned long long v = ld_pair(&h_pub[p * HID + u0]);
        h_lds[p][l0]     = __uint_as_float((unsigned)v);
        h_lds[p][l0 + 1] = __uint_as_float((unsigned)(v >> 32));
        __syncthreads();

        // ---- dot: 8 rows x 16 elems per thread
        float4 h4[4];
        #pragma unroll
        for (int q = 0; q < 4; q++)
            h4[q] = *(const float4*)&h_lds[p][ec * 20 + q * 4];

        float a[8];
        #pragma unroll
        for (int rr = 0; rr < 8; rr++) {
            float s0 = 0.f, s1 = 0.f, s2 = 0.f, s3 = 0.f;
            #pragma unroll
            for (int q = 0; q < 4; q++) {
                s0 = fmaf(w[rr][q].x, h4[q].x, s0);
                s1 = fmaf(w[rr][q].y, h4[q].y, s1);
                s2 = fmaf(w[rr][q].z, h4[q].z, s2);
                s3 = fmaf(w[rr][q].w, h4[q].w, s3);
            }
            a[rr] = (s0 + s1) + (s2 + s3);
        }

        // ---- multi-value fold: 8 accs x 64 lanes -> lane ec holds row ec&7
        const bool b0 = (ec & 1), b1 = (ec & 2), b2 = (ec & 4);
        float f[4];
        #pragma unroll
        for (int i = 0; i < 4; i++) {
            float send = b0 ? a[2*i] : a[2*i+1];
            float recv = __shfl_xor(send, 1, 64);
            f[i] = (b0 ? a[2*i+1] : a[2*i]) + recv;
        }
        float g2[2];
        #pragma unroll
        for (int i = 0; i < 2; i++) {
            float send = b1 ? f[2*i] : f[2*i+1];
            float recv = __shfl_xor(send, 2, 64);
            g2[i] = (b1 ? f[2*i+1] : f[2*i]) + recv;
        }
        float d;
        {
            float send = b2 ? g2[0] : g2[1];
            float recv = __shfl_xor(send, 4, 64);
            d = (b2 ? g2[1] : g2[0]) + recv;
        }
        d += __shfl_xor(d, 8, 64);
        d += __shfl_xor(d, 16, 64);
        d += __shfl_xor(d, 32, 64);
        d += xgv;                       // full preact for row grow[ec&7]

        // ---- gather {i,f,g,o} onto lanes 0 (unit 2rg) and 4 (unit 2rg+1)
        float v1g = __shfl_xor(d, 1, 64);
        float v2g = __shfl_xor(d, 2, 64);
        float v3g = __shfl_xor(d, 3, 64);

        if (ec == 0 || ec == 4) {
            float si = fsigmoid(d);
            float sf = fsigmoid(v1g);
            float tg = ftanh(v2g);
            float so = fsigmoid(v3g);
            c = sf * c + si * tg;
            float hn = so * ftanh(c);
            st_h(&h_pub[(p ^ 1) * HID + myunit], hn);
        }
        __syncthreads();                 // drain publish stores (vmcnt 0)
        if (thr == 0) add_ctr_rel(ctr);  // signal: this block's 16 units done
    }

    // ---- tail: block 0 computes pred = tanh(w_out . h_final + b_out)
    if (b == 0) {
        if (thr == 0) {
            const unsigned target = 64u * (unsigned)(T_STEPS + 1);
            while (ld_ctr_acq(ctr) < target) { }
        }
        __syncthreads();
        unsigned long long v = ld_pair(&h_pub[0 * HID + u0]);   // h_4096, buf 0
        float part = __uint_as_float((unsigned)v)        * w_out[u0]
                   + __uint_as_float((unsigned)(v >> 32)) * w_out[u0 + 1];
        #pragma unroll
        for (int m = 1; m < 64; m <<= 1)
            part += __shfl_xor(part, m, 64);
        if (ec == 0) red_lds[rg] = part;
        __syncthreads();
        if (thr == 0) {
            float s = 0.f;
            #pragma unroll
            for (int i = 0; i < 8; i++) s += red_lds[i];
            out[0] = tanhf(s + b_out[0]);
        }
    }
}

// ---------------------------------------------------------------------------
extern "C" void kernel_launch(void* const* d_in, const int* in_sizes, int n_in,
                              void* d_out, int out_size, void* d_ws, size_t ws_size,
                              hipStream_t stream) {
    const float* x     = (const float*)d_in[0];
    const float* h0    = (const float*)d_in[1];
    const float* c0    = (const float*)d_in[2];
    const float* w_ih  = (const float*)d_in[3];
    const float* w_hh  = (const float*)d_in[4];
    const float* b_ih  = (const float*)d_in[5];
    const float* b_hh  = (const float*)d_in[6];
    const float* w_out = (const float*)d_in[7];
    const float* b_out = (const float*)d_in[8];
    float* out = (float*)d_out;

    char* ws = (char*)d_ws;
    float*    xg    = (float*)ws;                                   // 64 MiB
    float*    h_pub = (float*)(ws + (size_t)T_STEPS * G4 * 4);      // 8 KiB
    unsigned* ctr   = (unsigned*)(ws + (size_t)T_STEPS * G4 * 4 + 12288); // own line

    xg_gemm<<<dim3(64, 64), 256, 0, stream>>>(x, w_ih, b_ih, b_hh, xg, ctr);
    lstm_rec<<<NB, TPB, 0, stream>>>(xg, w_hh, h0, c0, w_out, b_out,
                                     h_pub, ctr, out);
}

// Round 13
// 13708.920 us; speedup vs baseline: 1.2896x; 1.2896x over previous
//
#include <hip/hip_runtime.h>
#include <math.h>

#define T_STEPS 4096
#define HID     1024
#define G4      4096   // 4*HID gate rows
#define NB      64     // recurrence blocks
#define TPB     512    // 8 waves per block

// ---- tagged-word publish: one 64-bit atomic = {u32 step-tag | f32 value} ----
__device__ __forceinline__ unsigned long long ld64(const unsigned long long* p) {
    return __hip_atomic_load(p, __ATOMIC_RELAXED, __HIP_MEMORY_SCOPE_AGENT);
}
__device__ __forceinline__ void st64(unsigned long long* p, unsigned long long v) {
    __hip_atomic_store(p, v, __ATOMIC_RELAXED, __HIP_MEMORY_SCOPE_AGENT);
}
__device__ __forceinline__ unsigned long long packhv(float h, unsigned tag) {
    return ((unsigned long long)tag << 32) | (unsigned long long)__float_as_uint(h);
}
__device__ __forceinline__ float fsigmoid(float x) {
    return __fdividef(1.0f, 1.0f + __expf(-x));
}
__device__ __forceinline__ float ftanh(float x) {
    return __fdividef(2.0f, 1.0f + __expf(-2.0f * x)) - 1.0f;
}

// ---------------------------------------------------------------------------
// Kernel 1: xg[t][r] = dot(x[t,:], w_ih[r,:]) + b_ih[r] + b_hh[r]
// f32 GEMM, 64x64 tile, K-chunk 32, 256 threads, 4x4 per thread.
// Blocks (0, y<8) also zero h_pub (2x1024 u64) so each graph replay resets.
// ---------------------------------------------------------------------------
__global__ __launch_bounds__(256) void xg_gemm(
    const float* __restrict__ x, const float* __restrict__ w_ih,
    const float* __restrict__ b_ih, const float* __restrict__ b_hh,
    float* __restrict__ xg, unsigned long long* __restrict__ h_pub)
{
    if (blockIdx.x == 0 && blockIdx.y < 8)
        h_pub[blockIdx.y * 256 + threadIdx.x] = 0ull;

    __shared__ float Xs[32][68];   // [k][m], pad kills conflicts
    __shared__ float Ws[32][68];   // [k][n]

    const int t0  = blockIdx.y * 64;
    const int n0  = blockIdx.x * 64;
    const int thr = threadIdx.x;
    const int tx  = thr & 15;      // n-group
    const int ty  = thr >> 4;      // m-group

    float acc[4][4] = {};

    for (int kk = 0; kk < 1024; kk += 32) {
        #pragma unroll
        for (int i = 0; i < 2; i++) {
            int flat = thr + i * 256;       // 0..511
            int m    = flat >> 3;           // 0..63
            int kc   = flat & 7;            // k-chunk (4 floats)
            float4 xv = *(const float4*)(x    + (size_t)(t0 + m) * 1024 + kk + kc * 4);
            float4 wv = *(const float4*)(w_ih + (size_t)(n0 + m) * 1024 + kk + kc * 4);
            Xs[kc*4+0][m] = xv.x; Xs[kc*4+1][m] = xv.y;
            Xs[kc*4+2][m] = xv.z; Xs[kc*4+3][m] = xv.w;
            Ws[kc*4+0][m] = wv.x; Ws[kc*4+1][m] = wv.y;
            Ws[kc*4+2][m] = wv.z; Ws[kc*4+3][m] = wv.w;
        }
        __syncthreads();
        #pragma unroll
        for (int k = 0; k < 32; k++) {
            float4 a4 = *(const float4*)&Xs[k][ty * 4];
            float4 b4 = *(const float4*)&Ws[k][tx * 4];
            float av[4] = {a4.x, a4.y, a4.z, a4.w};
            float bv[4] = {b4.x, b4.y, b4.z, b4.w};
            #pragma unroll
            for (int i = 0; i < 4; i++)
                #pragma unroll
                for (int j = 0; j < 4; j++)
                    acc[i][j] = fmaf(av[i], bv[j], acc[i][j]);
        }
        __syncthreads();
    }

    float4 bi = *(const float4*)(b_ih + n0 + tx * 4);
    float4 bh = *(const float4*)(b_hh + n0 + tx * 4);
    float bb[4] = {bi.x + bh.x, bi.y + bh.y, bi.z + bh.z, bi.w + bh.w};
    #pragma unroll
    for (int i = 0; i < 4; i++) {
        float4 o;
        o.x = acc[i][0] + bb[0]; o.y = acc[i][1] + bb[1];
        o.z = acc[i][2] + bb[2]; o.w = acc[i][3] + bb[3];
        *(float4*)(xg + (size_t)(t0 + ty * 4 + i) * G4 + n0 + tx * 4) = o;
    }
}

// ---------------------------------------------------------------------------
// Kernel 2: persistent recurrence. 64 blocks x 512 threads, r2's proven
// tagged-word handoff (best measured: 2.03 us/step), with the weight
// stream moved OFF L2:
//   rows 0..3 (unit 2rg):  float4 w4[4][4] resident in VGPRs
//                          (r7-proven shape, __launch_bounds__(512,1) cap)
//   rows 4..7 (unit 2rg+1): per-thread private LDS region, 17 float4s
//                          (stride 68 words -> 16B aligned, start banks
//                          tile 32 banks per 8 lanes: aggregate-floor reads)
// LDS: 139KB weights + 10KB h staging -> 1 block/CU.
// Per step: xg prefetch -> poll own 2 tagged words -> stage h -> barrier ->
// 8x16 dot (4 reg rows + 4 LDS rows) -> 10-shuffle fold -> 3-shuffle
// gather -> gates on lanes 0/4 -> fire-and-forget tagged publish.
// ONE barrier per step, no fences.
// ---------------------------------------------------------------------------
__global__ __launch_bounds__(512, 1) void lstm_rec(
    const float* __restrict__ xg, const float* __restrict__ w_hh,
    const float* __restrict__ h0, const float* __restrict__ c0,
    const float* __restrict__ w_out, const float* __restrict__ b_out,
    unsigned long long* __restrict__ h_pub,   // [2][HID] tagged words
    float* __restrict__ out)
{
    __shared__ float4 w_lds4[512 * 17];   // 139,264 B: per-thread weight regions
    __shared__ float  h_lds[2][64 * 20];  // 10,240 B: double-buffered h
    __shared__ float  red_lds[8];

    const int thr = threadIdx.x;
    const int b   = blockIdx.x;
    const int rg  = thr >> 6;          // wave 0..7
    const int ec  = thr & 63;          // lane 0..63

    // this wave's 8 rows: gate = rr&3, unit-delta = rr>>2
    int grow[8];
    #pragma unroll
    for (int rr = 0; rr < 8; rr++)
        grow[rr] = (rr & 3) * HID + b * 16 + 2 * rg + (rr >> 2);

    // ---- rows 0..3 (unit 2rg) -> registers
    float4 w4[4][4];
    #pragma unroll
    for (int rr = 0; rr < 4; rr++) {
        const float* wr = w_hh + (size_t)grow[rr] * HID + ec * 16;
        #pragma unroll
        for (int q = 0; q < 4; q++)
            w4[rr][q] = *(const float4*)(wr + q * 4);
    }
    // ---- rows 4..7 (unit 2rg+1) -> own LDS region (written+read by this
    // thread only: no barrier needed on this path)
    #pragma unroll
    for (int rr = 0; rr < 4; rr++) {
        const float* wr = w_hh + (size_t)grow[4 + rr] * HID + ec * 16;
        #pragma unroll
        for (int q = 0; q < 4; q++)
            w_lds4[thr * 17 + rr * 4 + q] = *(const float4*)(wr + q * 4);
    }

    // ---- init: c lives on lanes 0 and 4 of each wave
    const int myunit = b * 16 + 2 * rg + (ec >> 2);   // valid on lanes 0,4
    float c = 0.0f;
    if (ec == 0 || ec == 4) {
        c = c0[myunit];
        st64(&h_pub[0 * HID + myunit], packhv(h0[myunit], 1u));
    }

    const int u0 = 2 * thr;            // this thread's two staged h units
    const int l0 = (u0 >> 4) * 20 + (u0 & 15);
    const int xrow = grow[ec & 7];     // xg row whose total this lane holds

    for (int t = 0; t < T_STEPS; t++) {
        const int p = t & 1;

        // xg prefetch (independent of the handoff)
        float xgv = xg[(size_t)t * G4 + xrow];

        // ---- spin on own two tagged words
        const unsigned tag = (unsigned)(t + 1);
        const unsigned long long* a0 = &h_pub[p * HID + u0];
        unsigned long long v0 = ld64(a0), v1 = ld64(a0 + 1);
        while (((unsigned)(v0 >> 32) != tag) | ((unsigned)(v1 >> 32) != tag)) {
            v0 = ld64(a0); v1 = ld64(a0 + 1);
        }
        h_lds[p][l0]     = __uint_as_float((unsigned)v0);
        h_lds[p][l0 + 1] = __uint_as_float((unsigned)v1);
        __syncthreads();

        // ---- h fragment: 16 floats
        float4 h4[4];
        #pragma unroll
        for (int q = 0; q < 4; q++)
            h4[q] = *(const float4*)&h_lds[p][ec * 20 + q * 4];

        float a[8];
        // rows 0..3 from registers
        #pragma unroll
        for (int rr = 0; rr < 4; rr++) {
            float s0 = 0.f, s1 = 0.f, s2 = 0.f, s3 = 0.f;
            #pragma unroll
            for (int q = 0; q < 4; q++) {
                s0 = fmaf(w4[rr][q].x, h4[q].x, s0);
                s1 = fmaf(w4[rr][q].y, h4[q].y, s1);
                s2 = fmaf(w4[rr][q].z, h4[q].z, s2);
                s3 = fmaf(w4[rr][q].w, h4[q].w, s3);
            }
            a[rr] = (s0 + s1) + (s2 + s3);
        }
        // rows 4..7 from own LDS region (conflict-floor ds_read_b128)
        #pragma unroll
        for (int rr = 0; rr < 4; rr++) {
            float s0 = 0.f, s1 = 0.f, s2 = 0.f, s3 = 0.f;
            #pragma unroll
            for (int q = 0; q < 4; q++) {
                float4 wl = w_lds4[thr * 17 + rr * 4 + q];
                s0 = fmaf(wl.x, h4[q].x, s0);
                s1 = fmaf(wl.y, h4[q].y, s1);
                s2 = fmaf(wl.z, h4[q].z, s2);
                s3 = fmaf(wl.w, h4[q].w, s3);
            }
            a[4 + rr] = (s0 + s1) + (s2 + s3);
        }

        // ---- multi-value fold: 8 accs x 64 lanes -> lane ec holds row ec&7
        const bool b0 = (ec & 1), b1 = (ec & 2), b2 = (ec & 4);
        float f[4];
        #pragma unroll
        for (int i = 0; i < 4; i++) {
            float send = b0 ? a[2*i] : a[2*i+1];
            float recv = __shfl_xor(send, 1, 64);
            f[i] = (b0 ? a[2*i+1] : a[2*i]) + recv;
        }
        float g2[2];
        #pragma unroll
        for (int i = 0; i < 2; i++) {
            float send = b1 ? f[2*i] : f[2*i+1];
            float recv = __shfl_xor(send, 2, 64);
            g2[i] = (b1 ? f[2*i+1] : f[2*i]) + recv;
        }
        float d;
        {
            float send = b2 ? g2[0] : g2[1];
            float recv = __shfl_xor(send, 4, 64);
            d = (b2 ? g2[1] : g2[0]) + recv;
        }
        d += __shfl_xor(d, 8, 64);
        d += __shfl_xor(d, 16, 64);
        d += __shfl_xor(d, 32, 64);
        d += xgv;                       // full preact for row grow[ec&7]

        // ---- gather {i,f,g,o} onto lanes 0 (unit 2rg) and 4 (unit 2rg+1)
        float v1g = __shfl_xor(d, 1, 64);
        float v2g = __shfl_xor(d, 2, 64);
        float v3g = __shfl_xor(d, 3, 64);

        if (ec == 0 || ec == 4) {
            float si = fsigmoid(d);
            float sf = fsigmoid(v1g);
            float tg = ftanh(v2g);
            float so = fsigmoid(v3g);
            c = sf * c + si * tg;
            float hn = so * ftanh(c);
            st64(&h_pub[(p ^ 1) * HID + myunit], packhv(hn, (unsigned)(t + 2)));
        }
    }

    // ---- tail: block 0 computes pred = tanh(w_out . h_final + b_out)
    if (b == 0) {
        const unsigned tag = (unsigned)(T_STEPS + 1);    // final h in buffer 0
        const unsigned long long* a0 = &h_pub[0 * HID + u0];
        unsigned long long v0 = ld64(a0), v1 = ld64(a0 + 1);
        while (((unsigned)(v0 >> 32) != tag) | ((unsigned)(v1 >> 32) != tag)) {
            v0 = ld64(a0); v1 = ld64(a0 + 1);
        }
        float part = __uint_as_float((unsigned)v0) * w_out[u0]
                   + __uint_as_float((unsigned)v1) * w_out[u0 + 1];
        #pragma unroll
        for (int m = 1; m < 64; m <<= 1)
            part += __shfl_xor(part, m, 64);
        __syncthreads();
        if (ec == 0) red_lds[rg] = part;
        __syncthreads();
        if (thr == 0) {
            float s = 0.f;
            #pragma unroll
            for (int i = 0; i < 8; i++) s += red_lds[i];
            out[0] = tanhf(s + b_out[0]);
        }
    }
}

// ---------------------------------------------------------------------------
extern "C" void kernel_launch(void* const* d_in, const int* in_sizes, int n_in,
                              void* d_out, int out_size, void* d_ws, size_t ws_size,
                              hipStream_t stream) {
    const float* x     = (const float*)d_in[0];
    const float* h0    = (const float*)d_in[1];
    const float* c0    = (const float*)d_in[2];
    const float* w_ih  = (const float*)d_in[3];
    const float* w_hh  = (const float*)d_in[4];
    const float* b_ih  = (const float*)d_in[5];
    const float* b_hh  = (const float*)d_in[6];
    const float* w_out = (const float*)d_in[7];
    const float* b_out = (const float*)d_in[8];
    float* out = (float*)d_out;

    char* ws = (char*)d_ws;
    float*              xg    = (float*)ws;                               // 64 MiB
    unsigned long long* h_pub = (unsigned long long*)(ws + (size_t)T_STEPS * G4 * 4);  // 16 KiB

    xg_gemm<<<dim3(64, 64), 256, 0, stream>>>(x, w_ih, b_ih, b_hh, xg, h_pub);
    lstm_rec<<<NB, TPB, 0, stream>>>(xg, w_hh, h0, c0, w_out, b_out, h_pub, out);
}